// Round 2
// baseline (386.832 us; speedup 1.0000x reference)
//
#include <hip/hip_runtime.h>

#define BB 2
#define SS 2048
#define EE 1024
#define HH 16
#define DD 64

typedef unsigned short u16;
typedef float f4 __attribute__((ext_vector_type(4)));
typedef __bf16 b8 __attribute__((ext_vector_type(8)));
typedef short s8i __attribute__((ext_vector_type(8)));

__device__ inline u16 f2b(float f) {
  unsigned u = __builtin_bit_cast(unsigned, f);
  unsigned r = (u + 0x7fffu + ((u >> 16) & 1u)) >> 16;
  return (u16)r;
}

// ---------------- prep: casts + weight transposes ----------------
__global__ void prep(const float* __restrict__ x,
                     const float* __restrict__ Wq, const float* __restrict__ Wk,
                     const float* __restrict__ Wv, const float* __restrict__ Wo,
                     u16* __restrict__ xb, u16* __restrict__ Wt, u16* __restrict__ Wot) {
  int tid = blockIdx.x * blockDim.x + threadIdx.x;
  int stride = gridDim.x * blockDim.x;
  const int NX = BB * SS * EE;                 // 4,194,304
  for (int i = tid; i < NX; i += stride) xb[i] = f2b(x[i]);
  const int NW = 3 * HH * DD * EE;             // 3,145,728 : Wt[n][e], n=(qkv,h,d)
  for (int i = tid; i < NW; i += stride) {
    int n = i >> 10, e = i & 1023;
    int qkv = n >> 10, hd = n & 1023;
    int h = hd >> 6, d = hd & 63;
    const float* W = (qkv == 0) ? Wq : (qkv == 1) ? Wk : Wv;
    Wt[i] = f2b(W[(h * EE + e) * DD + d]);
  }
  const int NO = HH * DD * EE;                 // Wot[n=c][k=e] = Wo[e][c]
  for (int i = tid; i < NO; i += stride) {
    int e = i >> 10, c = i & 1023;
    Wot[i] = f2b(Wo[c * EE + e]);
  }
}

// ---------------- 128x128 bf16 MFMA GEMM (A,B row-major in K=1024) ------------
// MODE 0: C -> Q/K/V bf16 [B,H,S,D] + bias(bq/bk/bv)
// MODE 1: C -> fp32 out [4096,1024] + bo
template <int MODE>
__global__ __launch_bounds__(256) void gemm128(
    const u16* __restrict__ A, const u16* __restrict__ Bm,
    u16* __restrict__ Qo, u16* __restrict__ Ko, u16* __restrict__ Vo,
    const float* __restrict__ bq, const float* __restrict__ bk,
    const float* __restrict__ bv,
    float* __restrict__ Co, const float* __restrict__ bo) {
  const int K = 1024;
  __shared__ u16 As[128 * 32];
  __shared__ u16 Bs[128 * 32];
  int t = threadIdx.x;
  int lane = t & 63, w = t >> 6;
  int wr = w >> 1, wc = w & 1;
  int lr = lane & 15, lg = lane >> 4;
  int m0 = blockIdx.y * 128, n0 = blockIdx.x * 128;

  f4 acc[4][4];
  const f4 z4 = {0.f, 0.f, 0.f, 0.f};
  for (int mi = 0; mi < 4; ++mi)
    for (int ni = 0; ni < 4; ++ni) acc[mi][ni] = z4;

  // staging: 512 chunks of 16B per matrix; thread handles chunk t and t+256
  int r0 = t >> 2, s0 = t & 3;
  int r1 = (t + 256) >> 2, s1 = (t + 256) & 3;

  for (int ks = 0; ks < K / 32; ++ks) {
    int k0 = ks * 32;
    s8i av0 = *(const s8i*)(A + (size_t)(m0 + r0) * K + k0 + s0 * 8);
    s8i av1 = *(const s8i*)(A + (size_t)(m0 + r1) * K + k0 + s1 * 8);
    s8i bv0 = *(const s8i*)(Bm + (size_t)(n0 + r0) * K + k0 + s0 * 8);
    s8i bv1 = *(const s8i*)(Bm + (size_t)(n0 + r1) * K + k0 + s1 * 8);
    *(s8i*)&As[r0 * 32 + s0 * 8] = av0;
    *(s8i*)&As[r1 * 32 + s1 * 8] = av1;
    *(s8i*)&Bs[r0 * 32 + s0 * 8] = bv0;
    *(s8i*)&Bs[r1 * 32 + s1 * 8] = bv1;
    __syncthreads();
    b8 af[4], bf[4];
    for (int mi = 0; mi < 4; ++mi)
      af[mi] = *(const b8*)&As[(wr * 64 + mi * 16 + lr) * 32 + lg * 8];
    for (int ni = 0; ni < 4; ++ni)
      bf[ni] = *(const b8*)&Bs[(wc * 64 + ni * 16 + lr) * 32 + lg * 8];
    for (int mi = 0; mi < 4; ++mi)
      for (int ni = 0; ni < 4; ++ni)
        acc[mi][ni] = __builtin_amdgcn_mfma_f32_16x16x32_bf16(af[mi], bf[ni],
                                                              acc[mi][ni], 0, 0, 0);
    __syncthreads();
  }

  for (int mi = 0; mi < 4; ++mi)
    for (int ni = 0; ni < 4; ++ni)
      for (int r = 0; r < 4; ++r) {
        int m_g = m0 + wr * 64 + mi * 16 + lg * 4 + r;
        int n_g = n0 + wc * 64 + ni * 16 + lr;
        float v = acc[mi][ni][r];
        if (MODE == 0) {
          int qkv = n_g >> 10, hd = n_g & 1023;
          const float* bias = (qkv == 0) ? bq : (qkv == 1) ? bk : bv;
          v += bias[hd];
          int b = m_g >> 11, s = m_g & 2047;
          u16* dst = (qkv == 0) ? Qo : (qkv == 1) ? Ko : Vo;
          dst[(((size_t)b * HH + (hd >> 6)) * SS + s) * DD + (hd & 63)] = f2b(v);
        } else {
          Co[(size_t)m_g * 1024 + n_g] = v + bo[n_g];
        }
      }
}

// ---------------- flash attention (causal), 64 q-rows/block -------------------
__global__ __launch_bounds__(256) void fattn(const u16* __restrict__ Qb,
                                             const u16* __restrict__ Kb,
                                             const u16* __restrict__ Vb,
                                             u16* __restrict__ AO) {
  __shared__ u16 Kl[32 * 72];      // [kv][d], padded 64->72 (2-way max)
  __shared__ u16 Vt[64 * 40];      // [d][kv], padded 32->40
  __shared__ u16 Pl[4][16 * 40];   // per-wave P [qrow][kv], padded

  int t = threadIdx.x, lane = t & 63, w = t >> 6;
  int lr = lane & 15, lg = lane >> 4;
  int qt = blockIdx.x, bh = blockIdx.y;
  int b = bh >> 4, h = bh & 15;
  int qbase = qt * 64;
  size_t base = (size_t)bh * SS * DD;

  // Q fragments in registers: row = lr, k(d) = kc*32 + lg*8 + j
  int qrow = qbase + w * 16 + lr;
  const u16* qp = Qb + base + (size_t)qrow * DD;
  b8 qf0 = *(const b8*)(qp + lg * 8);
  b8 qf1 = *(const b8*)(qp + 32 + lg * 8);

  const f4 z4 = {0.f, 0.f, 0.f, 0.f};
  f4 o[4];
  for (int i = 0; i < 4; ++i) o[i] = z4;
  float mrow[4], lsum[4];
  for (int r = 0; r < 4; ++r) { mrow[r] = -1e30f; lsum[r] = 0.f; }

  int srow = t >> 3, ssl = t & 7;  // staging: row 0..31, 16B slot 0..7
  int ntile = 2 * qt + 2;
  for (int kt = 0; kt < ntile; ++kt) {
    int kv0 = kt * 32;
    // stage K row-major, V transposed
    s8i kvv = *(const s8i*)(Kb + base + (size_t)(kv0 + srow) * DD + ssl * 8);
    s8i vvv = *(const s8i*)(Vb + base + (size_t)(kv0 + srow) * DD + ssl * 8);
    *(s8i*)&Kl[srow * 72 + ssl * 8] = kvv;
    for (int j = 0; j < 8; ++j)
      Vt[(ssl * 8 + j) * 40 + srow] = (u16)vvv[j];
    __syncthreads();

    // S = Q K^T  (two 16-col tiles, two 32-k chunks)
    f4 sa0 = z4, sa1 = z4;
    {
      b8 kf = *(const b8*)&Kl[(lr) * 72 + lg * 8];
      sa0 = __builtin_amdgcn_mfma_f32_16x16x32_bf16(qf0, kf, sa0, 0, 0, 0);
      kf = *(const b8*)&Kl[(lr) * 72 + 32 + lg * 8];
      sa0 = __builtin_amdgcn_mfma_f32_16x16x32_bf16(qf1, kf, sa0, 0, 0, 0);
      kf = *(const b8*)&Kl[(16 + lr) * 72 + lg * 8];
      sa1 = __builtin_amdgcn_mfma_f32_16x16x32_bf16(qf0, kf, sa1, 0, 0, 0);
      kf = *(const b8*)&Kl[(16 + lr) * 72 + 32 + lg * 8];
      sa1 = __builtin_amdgcn_mfma_f32_16x16x32_bf16(qf1, kf, sa1, 0, 0, 0);
    }

    // online softmax; row r_global = qbase + w*16 + lg*4 + r, col = kv0 + nt*16 + lr
    float scl[4];
    int qg = qbase + w * 16 + lg * 4;
    for (int r = 0; r < 4; ++r) {
      float v0 = sa0[r] * 0.125f;
      float v1 = sa1[r] * 0.125f;
      int q = qg + r;
      if (kv0 + lr > q) v0 = -1e30f;
      if (kv0 + 16 + lr > q) v1 = -1e30f;
      float mx = fmaxf(v0, v1);
      mx = fmaxf(mx, __shfl_xor(mx, 1));
      mx = fmaxf(mx, __shfl_xor(mx, 2));
      mx = fmaxf(mx, __shfl_xor(mx, 4));
      mx = fmaxf(mx, __shfl_xor(mx, 8));
      float mn = fmaxf(mrow[r], mx);
      float sc = __expf(mrow[r] - mn);
      float p0 = __expf(v0 - mn);
      float p1 = __expf(v1 - mn);
      float ps = p0 + p1;
      ps += __shfl_xor(ps, 1);
      ps += __shfl_xor(ps, 2);
      ps += __shfl_xor(ps, 4);
      ps += __shfl_xor(ps, 8);
      lsum[r] = lsum[r] * sc + ps;
      mrow[r] = mn;
      scl[r] = sc;
      Pl[w][(lg * 4 + r) * 40 + lr] = f2b(p0);
      Pl[w][(lg * 4 + r) * 40 + 16 + lr] = f2b(p1);
    }
    for (int nt = 0; nt < 4; ++nt) {
      f4 ov = o[nt];
      for (int r = 0; r < 4; ++r) ov[r] *= scl[r];
      o[nt] = ov;
    }

    // PV: P[16x32] @ V[32x64]
    b8 pf = *(const b8*)&Pl[w][lr * 40 + lg * 8];
    for (int nt = 0; nt < 4; ++nt) {
      b8 vf = *(const b8*)&Vt[(nt * 16 + lr) * 40 + lg * 8];
      o[nt] = __builtin_amdgcn_mfma_f32_16x16x32_bf16(pf, vf, o[nt], 0, 0, 0);
    }
    __syncthreads();
  }

  // epilogue -> AO [B,S,H*D] bf16
  for (int nt = 0; nt < 4; ++nt)
    for (int r = 0; r < 4; ++r) {
      int qgr = qbase + w * 16 + lg * 4 + r;
      int d = nt * 16 + lr;
      float val = o[nt][r] / lsum[r];
      AO[((size_t)b * SS + qgr) * (HH * DD) + h * DD + d] = f2b(val);
    }
}

// ---------------- launch ----------------
extern "C" void kernel_launch(void* const* d_in, const int* in_sizes, int n_in,
                              void* d_out, int out_size, void* d_ws, size_t ws_size,
                              hipStream_t stream) {
  const float* x  = (const float*)d_in[0];
  const float* Wq = (const float*)d_in[1];
  const float* Wk = (const float*)d_in[2];
  const float* Wv = (const float*)d_in[3];
  const float* bq = (const float*)d_in[4];
  const float* bk = (const float*)d_in[5];
  const float* bv = (const float*)d_in[6];
  const float* Wo = (const float*)d_in[7];
  const float* bo = (const float*)d_in[8];

  char* ws = (char*)d_ws;
  u16* xb  = (u16*)(ws);                    // 8 MiB  (aliased later by AO)
  u16* Wt  = (u16*)(ws + ((size_t)8 << 20));   // 6 MiB
  u16* Wot = (u16*)(ws + ((size_t)14 << 20));  // 2 MiB
  u16* Qw  = (u16*)(ws + ((size_t)16 << 20));  // 8 MiB
  u16* Kw  = (u16*)(ws + ((size_t)24 << 20));  // 8 MiB
  u16* Vw  = (u16*)(ws + ((size_t)32 << 20));  // 8 MiB
  u16* AO  = xb;  // safe: fattn runs entirely after gemm128<0> consumed xb

  prep<<<2048, 256, 0, stream>>>(x, Wq, Wk, Wv, Wo, xb, Wt, Wot);
  gemm128<0><<<dim3(24, 32), 256, 0, stream>>>(xb, Wt, Qw, Kw, Vw, bq, bk, bv,
                                               nullptr, nullptr);
  fattn<<<dim3(32, 32), 256, 0, stream>>>(Qw, Kw, Vw, AO);
  gemm128<1><<<dim3(8, 32), 256, 0, stream>>>(AO, Wot, nullptr, nullptr, nullptr,
                                              nullptr, nullptr, nullptr,
                                              (float*)d_out, bo);
}